// Round 3
// baseline (418.036 us; speedup 1.0000x reference)
//
#include <hip/hip_runtime.h>
#include <math.h>

typedef _Float16 f16_t;
typedef _Float16 half8 __attribute__((ext_vector_type(8)));
typedef float f32x4 __attribute__((ext_vector_type(4)));
typedef unsigned short u16;

#define T_SEQ 2048
#define H_DIM 2048
#define C_DIM 1024
#define B_SZ  4

// async global->LDS, 16B per lane. LDS dest = wave-uniform base + lane*16.
__device__ __forceinline__ void gload16(const void* g, void* l) {
  typedef const __attribute__((address_space(1))) unsigned int* gp_t;
  typedef __attribute__((address_space(3))) unsigned int* lp_t;
  __builtin_amdgcn_global_load_lds((gp_t)(unsigned long long)g,
                                   (lp_t)(unsigned int)(unsigned long long)l,
                                   16, 0, 0);
}

// LDS bank-conflict swizzle: LDS[row][c] holds global chunk c ^ ((row>>1)&3).
// Staged by fetching the permuted global chunk (still coalesced within the
// 64B row); ds_read de-swizzles. An 8-lane b128 phase covers all 32 banks.

// ---------------- 4-wave core (256 thr): 128x128 tile, BK=32 ----------------
__device__ __forceinline__ void gemm_tile(const f16_t* __restrict__ A,
                                          const f16_t* __restrict__ B,
                                          int K, int k_end, int m0, int n0,
                                          char* lds, f32x4 acc[4][4]) {
  const int tid  = threadIdx.x;
  const int wave = tid >> 6;
  const int lane = tid & 63;
  const int wm = (wave & 1) << 6;
  const int wn = (wave >> 1) << 6;
  const int srow = tid >> 2;
  const int scol = ((tid & 3) ^ ((tid >> 3) & 3)) << 3;     // swizzled fetch chunk
  const int fm = lane & 15;
  const int fks = (((lane >> 4) ^ ((lane >> 1) & 3)) << 3); // swizzled read offset
  const f16_t* As = (const f16_t*)lds;           // [128][32]
  const f16_t* Bs = (const f16_t*)(lds + 8192);  // [128][32]
  char* ldsA = lds + (wave << 10);
  char* ldsB = lds + 8192 + (wave << 10);
  const f16_t* Ap0 = A + (size_t)(m0 + srow) * K + scol;
  const f16_t* Ap1 = A + (size_t)(m0 + 64 + srow) * K + scol;
  const f16_t* Bp0 = B + (size_t)(n0 + srow) * K + scol;
  const f16_t* Bp1 = B + (size_t)(n0 + 64 + srow) * K + scol;
  for (int k0 = 0; k0 < k_end; k0 += 32) {
    gload16(Ap0 + k0, ldsA);
    gload16(Ap1 + k0, ldsA + 4096);
    gload16(Bp0 + k0, ldsB);
    gload16(Bp1 + k0, ldsB + 4096);
    __syncthreads();
    half8 af[4], bfr[4];
#pragma unroll
    for (int i = 0; i < 4; ++i)
      af[i] = *(const half8*)(As + ((wm + i * 16 + fm) << 5) + fks);
#pragma unroll
    for (int j = 0; j < 4; ++j)
      bfr[j] = *(const half8*)(Bs + ((wn + j * 16 + fm) << 5) + fks);
#pragma unroll
    for (int i = 0; i < 4; ++i)
#pragma unroll
      for (int j = 0; j < 4; ++j)
        acc[i][j] = __builtin_amdgcn_mfma_f32_16x16x32_f16(af[i], bfr[j], acc[i][j], 0, 0, 0);
    __syncthreads();
  }
}

// ------- 8-wave split-K core (512 thr): two groups halve K, LDS-reduce ------
__device__ __forceinline__ void gemm_tile_sk2(const f16_t* __restrict__ A,
                                              const f16_t* __restrict__ B,
                                              int K, int k_end, int m0, int n0,
                                              char* lds, f32x4 acc[4][4]) {
  const int tid  = threadIdx.x;            // 0..511
  const int grp  = tid >> 8;               // 0,1  (waves 0-3 / 4-7)
  const int ltid = tid & 255;
  const int wl   = ltid >> 6;              // local wave 0..3
  const int lane = tid & 63;
  const int wm = (wl & 1) << 6;
  const int wn = (wl >> 1) << 6;
  const int srow = ltid >> 2;
  const int scol = ((ltid & 3) ^ ((ltid >> 3) & 3)) << 3;   // swizzled fetch chunk
  const int fm = lane & 15;
  const int fks = (((lane >> 4) ^ ((lane >> 1) & 3)) << 3); // swizzled read offset
  const int khalf = k_end >> 1;            // multiple of 64
  const f16_t* As = (const f16_t*)(lds + grp * 16384);
  const f16_t* Bs = (const f16_t*)(lds + grp * 16384 + 8192);
  char* ldsA = lds + grp * 16384 + (wl << 10);
  char* ldsB = lds + grp * 16384 + 8192 + (wl << 10);
  const int kb = grp * khalf;
  const f16_t* Ap0 = A + (size_t)(m0 + srow) * K + kb + scol;
  const f16_t* Ap1 = A + (size_t)(m0 + 64 + srow) * K + kb + scol;
  const f16_t* Bp0 = B + (size_t)(n0 + srow) * K + kb + scol;
  const f16_t* Bp1 = B + (size_t)(n0 + 64 + srow) * K + kb + scol;
  for (int k0 = 0; k0 < khalf; k0 += 32) {
    gload16(Ap0 + k0, ldsA);
    gload16(Ap1 + k0, ldsA + 4096);
    gload16(Bp0 + k0, ldsB);
    gload16(Bp1 + k0, ldsB + 4096);
    __syncthreads();
    half8 af[4], bfr[4];
#pragma unroll
    for (int i = 0; i < 4; ++i)
      af[i] = *(const half8*)(As + ((wm + i * 16 + fm) << 5) + fks);
#pragma unroll
    for (int j = 0; j < 4; ++j)
      bfr[j] = *(const half8*)(Bs + ((wn + j * 16 + fm) << 5) + fks);
#pragma unroll
    for (int i = 0; i < 4; ++i)
#pragma unroll
      for (int j = 0; j < 4; ++j)
        acc[i][j] = __builtin_amdgcn_mfma_f32_16x16x32_f16(af[i], bfr[j], acc[i][j], 0, 0, 0);
    __syncthreads();
  }
  // Reduce grp1 partials into grp0. Two rounds of 2 quads (2 x 16 KB in LDS).
  float* red = (float*)lds;
#pragma unroll
  for (int round = 0; round < 2; ++round) {
    const int q0 = round << 1;
    if (grp == 1 && (wl == q0 || wl == q0 + 1)) {
      float* dst = red + (wl - q0) * 4096;
#pragma unroll
      for (int i = 0; i < 4; ++i)
#pragma unroll
        for (int j = 0; j < 4; ++j)
          *(f32x4*)(dst + (((i << 2) + j) << 8) + (lane << 2)) = acc[i][j];
    }
    __syncthreads();
    if (grp == 0 && (wl == q0 || wl == q0 + 1)) {
      const float* src = red + (wl - q0) * 4096;
#pragma unroll
      for (int i = 0; i < 4; ++i)
#pragma unroll
        for (int j = 0; j < 4; ++j) {
          const f32x4 p = *(const f32x4*)(src + (((i << 2) + j) << 8) + (lane << 2));
          acc[i][j] += p;
        }
    }
    __syncthreads();
  }
}

// C/D layout (verified m89): col = lane&15, row = (lane>>4)*4 + reg
#define EPI_PREAMBLE                                            \
  const int lane = threadIdx.x & 63;                            \
  const int wl_e = (threadIdx.x >> 6) & 3;                      \
  const int mb = m0 + ((wl_e & 1) << 6) + ((lane >> 4) << 2);   \
  const int nb = n0 + ((wl_e >> 1) << 6) + (lane & 15);

#define ZERO_ACC                                                \
  f32x4 acc[4][4];                                              \
  _Pragma("unroll")                                             \
  for (int i = 0; i < 4; ++i)                                   \
    _Pragma("unroll")                                           \
    for (int j = 0; j < 4; ++j) acc[i][j] = (f32x4){0.f, 0.f, 0.f, 0.f};

// Merged Q/K/V projection, XCD-remapped: XCD f&7 owns 8 consecutive m-strips
// so each X-strip stays in one XCD's L2.
__global__ __launch_bounds__(256, 2)
void k_proj(const f16_t* __restrict__ X,
            const f16_t* __restrict__ Wq, const f16_t* __restrict__ Wk,
            const f16_t* __restrict__ Wv,
            f16_t* __restrict__ Qo, f16_t* __restrict__ Ko,
            u16* __restrict__ Vt) {
  __shared__ char lds[16384];
  ZERO_ACC
  const int f = blockIdx.x + (blockIdx.y << 4) + (blockIdx.z << 10); // 0..3071
  const int xcd  = f & 7;
  const int slot = f >> 3;           // 0..383
  const int yg   = slot / 48;        // 0..7
  const int xz   = slot - yg * 48;   // 0..47
  const int y = (xcd << 3) + yg;     // m-strip 0..63
  const int x = xz & 15;             // n-tile 0..15
  const int z = xz >> 4;             // 0..2 (Q,K,V)
  const f16_t* W = (z == 0) ? Wq : (z == 1) ? Wk : Wv;
  const int m0 = y << 7, n0 = x << 7;
  gemm_tile(X, W, C_DIM, C_DIM, m0, n0, lds, acc);
  EPI_PREAMBLE
  if (z < 2) {
    f16_t* Cb = z ? Ko : Qo;
#pragma unroll
    for (int i = 0; i < 4; ++i)
#pragma unroll
      for (int j = 0; j < 4; ++j) {
        const size_t base = (size_t)(mb + i * 16) * H_DIM + (nb + j * 16);
#pragma unroll
        for (int r = 0; r < 4; ++r)
          Cb[base + (size_t)r * H_DIM] = (f16_t)acc[i][j][r];
      }
  } else {
#pragma unroll
    for (int i = 0; i < 4; ++i) {
      const int gm = mb + i * 16;          // b*T + t
      const int b = gm >> 11;
      const int t = gm & (T_SEQ - 1);
#pragma unroll
      for (int j = 0; j < 4; ++j) {
        const int h = nb + j * 16;
        ushort4 pk;
        pk.x = __builtin_bit_cast(u16, (f16_t)acc[i][j][0]);
        pk.y = __builtin_bit_cast(u16, (f16_t)acc[i][j][1]);
        pk.z = __builtin_bit_cast(u16, (f16_t)acc[i][j][2]);
        pk.w = __builtin_bit_cast(u16, (f16_t)acc[i][j][3]);
        *(ushort4*)(Vt + ((size_t)(b * H_DIM + h) * T_SEQ + t)) = pk;
      }
    }
  }
}

// scores: lower-triangle tiles only, 8-wave split-K. S fp32 (scaled).
__global__ __launch_bounds__(512, 4)
void k_scores(const f16_t* __restrict__ Q, const f16_t* __restrict__ Kc,
              float* __restrict__ S) {
  __shared__ char lds[32768];
  ZERO_ACC
  const int p = blockIdx.x;                // 0..135 lower-triangle tile id
  int i = (int)((sqrtf(8.f * p + 1.f) - 1.f) * 0.5f);
  while ((i + 1) * (i + 2) / 2 <= p) ++i;
  while (i * (i + 1) / 2 > p) --i;
  const int j = p - i * (i + 1) / 2;
  const int b = blockIdx.y;
  const int m0 = i << 7, n0 = j << 7;
  const f16_t* Aq = Q + (size_t)b * T_SEQ * H_DIM;
  const f16_t* Bk = Kc + (size_t)b * T_SEQ * H_DIM;
  float* Sb = S + (size_t)b * T_SEQ * T_SEQ;
  gemm_tile_sk2(Aq, Bk, H_DIM, H_DIM, m0, n0, lds, acc);
  if (threadIdx.x >> 8) return;            // grp1 has no sums
  EPI_PREAMBLE
  const float scale = 0.022097086912079608f;  // 2048^-0.5
#pragma unroll
  for (int i2 = 0; i2 < 4; ++i2)
#pragma unroll
    for (int j2 = 0; j2 < 4; ++j2) {
      const size_t base = (size_t)(mb + i2 * 16) * T_SEQ + (nb + j2 * 16);
#pragma unroll
      for (int r = 0; r < 4; ++r)
        Sb[base + (size_t)r * T_SEQ] = acc[i2][j2][r] * scale;
    }
}

// causal softmax row-wise: S fp32 -> P f16 (zeros above diagonal)
__global__ __launch_bounds__(256)
void k_softmax(const float* __restrict__ S, f16_t* __restrict__ P) {
  const int row = blockIdx.x;              // b*T + t
  const int t = row & (T_SEQ - 1);
  const int n = t + 1;
  const int tid = threadIdx.x;
  const float* s = S + (size_t)row * T_SEQ;
  f16_t* p = P + (size_t)row * T_SEQ;
  __shared__ float buf[T_SEQ];
  __shared__ float red[8];
  float lmax = -3.0e38f;
  for (int c = tid; c < n; c += 256) lmax = fmaxf(lmax, s[c]);
#pragma unroll
  for (int off = 32; off > 0; off >>= 1) lmax = fmaxf(lmax, __shfl_xor(lmax, off, 64));
  if ((tid & 63) == 0) red[tid >> 6] = lmax;
  __syncthreads();
  const float m = fmaxf(fmaxf(red[0], red[1]), fmaxf(red[2], red[3]));
  float lsum = 0.f;
  for (int c = tid; c < n; c += 256) {
    float e = __expf(s[c] - m);
    buf[c] = e;
    lsum += e;
  }
#pragma unroll
  for (int off = 32; off > 0; off >>= 1) lsum += __shfl_xor(lsum, off, 64);
  if ((tid & 63) == 0) red[4 + (tid >> 6)] = lsum;
  __syncthreads();
  const float inv = 1.0f / (red[4] + red[5] + red[6] + red[7]);
  for (int c = tid; c < T_SEQ; c += 256)
    p[c] = (c < n) ? (f16_t)(buf[c] * inv) : (f16_t)0.f;
}

// PV with diagonal pairing: block (n, q, b) computes m-tiles 15-q and q
// (uniform 17 tile-units of K per block; grid = 512 = one balanced round).
__global__ __launch_bounds__(512, 4)
void k_pv(const f16_t* __restrict__ P, const f16_t* __restrict__ Vt,
          float* __restrict__ Out) {
  __shared__ char lds[32768];
  const int b = blockIdx.z;
  const int n0 = blockIdx.x << 7;
  const f16_t* Ap = P + (size_t)b * T_SEQ * T_SEQ;
  const f16_t* Bv = Vt + (size_t)b * H_DIM * T_SEQ;
  float* Ob = Out + (size_t)b * T_SEQ * H_DIM;
#pragma unroll
  for (int u = 0; u < 2; ++u) {
    const int mi = u ? blockIdx.y : (15 - blockIdx.y);   // big K first
    const int m0 = mi << 7;
    ZERO_ACC
    gemm_tile_sk2(Ap, Bv, T_SEQ, m0 + 128, m0, n0, lds, acc);
    if (!(threadIdx.x >> 8)) {
      EPI_PREAMBLE
#pragma unroll
      for (int i = 0; i < 4; ++i)
#pragma unroll
        for (int j = 0; j < 4; ++j) {
          const size_t base = (size_t)(mb + i * 16) * H_DIM + (nb + j * 16);
#pragma unroll
          for (int r = 0; r < 4; ++r)
            Ob[base + (size_t)r * H_DIM] = acc[i][j][r];
        }
    }
  }
}

// one fused f32 -> f16 conversion pass over x, Wk, Wq, Wv
#define XN4 ((B_SZ * T_SEQ * C_DIM) / 4)   // 2097152
#define WN4 ((H_DIM * C_DIM) / 4)          // 524288
__global__ __launch_bounds__(256)
void k_cvt_all(const float4* __restrict__ x,  const float4* __restrict__ wk,
               const float4* __restrict__ wq, const float4* __restrict__ wv,
               ushort4* __restrict__ xb, ushort4* __restrict__ wkb,
               ushort4* __restrict__ wqb, ushort4* __restrict__ wvb) {
  int idx = blockIdx.x * 256 + threadIdx.x;
  const float4* src; ushort4* dst;
  if (idx < XN4)                { src = x;  dst = xb; }
  else if (idx < XN4 + WN4)     { src = wk; dst = wkb; idx -= XN4; }
  else if (idx < XN4 + 2 * WN4) { src = wq; dst = wqb; idx -= XN4 + WN4; }
  else                          { src = wv; dst = wvb; idx -= XN4 + 2 * WN4; }
  const float4 v = src[idx];
  ushort4 o;
  o.x = __builtin_bit_cast(u16, (f16_t)v.x);
  o.y = __builtin_bit_cast(u16, (f16_t)v.y);
  o.z = __builtin_bit_cast(u16, (f16_t)v.z);
  o.w = __builtin_bit_cast(u16, (f16_t)v.w);
  dst[idx] = o;
}

extern "C" void kernel_launch(void* const* d_in, const int* in_sizes, int n_in,
                              void* d_out, int out_size, void* d_ws, size_t ws_size,
                              hipStream_t stream) {
  (void)in_sizes; (void)n_in; (void)out_size; (void)ws_size;
  const float* x  = (const float*)d_in[0];
  const float* Wk = (const float*)d_in[1];
  const float* Wq = (const float*)d_in[2];
  const float* Wv = (const float*)d_in[3];
  float* out = (float*)d_out;
  char* ws = (char*)d_ws;
  // workspace (192 MB):
  //  [0,32M) q f16   [32M,64M) k f16   [64M,96M) Vt f16 [B,H,T]
  //  [96M,160M) S fp32 [B,T,T]         [160M,192M) P f16
  //  cvt temps (dead before S written): xb@96M, wk@112M, wq@116M, wv@120M
  f16_t* qb  = (f16_t*)(ws);
  f16_t* kb  = (f16_t*)(ws + (32ull << 20));
  f16_t* vt  = (f16_t*)(ws + (64ull << 20));
  float* S   = (float*)(ws + (96ull << 20));
  f16_t* P   = (f16_t*)(ws + (160ull << 20));
  f16_t* xb  = (f16_t*)(ws + (96ull << 20));
  f16_t* wkb = (f16_t*)(ws + (112ull << 20));
  f16_t* wqb = (f16_t*)(ws + (116ull << 20));
  f16_t* wvb = (f16_t*)(ws + (120ull << 20));

  k_cvt_all<<<(XN4 + 3 * WN4) / 256, 256, 0, stream>>>(
      (const float4*)x, (const float4*)Wk, (const float4*)Wq, (const float4*)Wv,
      (ushort4*)xb, (ushort4*)wkb, (ushort4*)wqb, (ushort4*)wvb);

  dim3 gp(H_DIM / 128, (B_SZ * T_SEQ) / 128, 3);       // 16 x 64 x 3 (remapped)
  k_proj<<<gp, 256, 0, stream>>>(xb, wqb, wkb, wvb, qb, kb, (u16*)vt);

  dim3 gs(136, B_SZ);                                   // lower-triangle tiles
  k_scores<<<gs, 512, 0, stream>>>(qb, kb, S);
  k_softmax<<<B_SZ * T_SEQ, 256, 0, stream>>>(S, P);
  dim3 gv(T_SEQ / 128, 8, B_SZ);                        // paired m-tiles
  k_pv<<<gv, 512, 0, stream>>>(P, vt, out);
}

// Round 4
// 411.388 us; speedup vs baseline: 1.0162x; 1.0162x over previous
//
#include <hip/hip_runtime.h>
#include <math.h>

typedef _Float16 f16_t;
typedef _Float16 half8 __attribute__((ext_vector_type(8)));
typedef float f32x4 __attribute__((ext_vector_type(4)));
typedef unsigned short u16;

#define T_SEQ 2048
#define H_DIM 2048
#define C_DIM 1024
#define B_SZ  4

// async global->LDS, 16B per lane. LDS dest = wave-uniform base + lane*16.
__device__ __forceinline__ void gload16(const void* g, void* l) {
  typedef const __attribute__((address_space(1))) unsigned int* gp_t;
  typedef __attribute__((address_space(3))) unsigned int* lp_t;
  __builtin_amdgcn_global_load_lds((gp_t)(unsigned long long)g,
                                   (lp_t)(unsigned int)(unsigned long long)l,
                                   16, 0, 0);
}

// LDS bank-conflict swizzle (R3: verified conflicts -> 0): LDS[row][c] holds
// global chunk c ^ ((row>>1)&3); fetch side permutes, ds_read de-swizzles.

// ------- 8-wave split-K core (512 thr): two groups halve K, LDS-reduce ------
// lds must be 32 KB. After return, waves 0-3 (grp 0) hold the full sums.
__device__ __forceinline__ void gemm_tile_sk2(const f16_t* __restrict__ A,
                                              const f16_t* __restrict__ B,
                                              int K, int k_end, int m0, int n0,
                                              char* lds, f32x4 acc[4][4]) {
  const int tid  = threadIdx.x;            // 0..511
  const int grp  = tid >> 8;               // 0,1  (waves 0-3 / 4-7)
  const int ltid = tid & 255;
  const int wl   = ltid >> 6;              // local wave 0..3
  const int lane = tid & 63;
  const int wm = (wl & 1) << 6;
  const int wn = (wl >> 1) << 6;
  const int srow = ltid >> 2;
  const int scol = ((ltid & 3) ^ ((ltid >> 3) & 3)) << 3;   // swizzled fetch chunk
  const int fm = lane & 15;
  const int fks = (((lane >> 4) ^ ((lane >> 1) & 3)) << 3); // swizzled read offset
  const int khalf = k_end >> 1;            // multiple of 32
  const f16_t* As = (const f16_t*)(lds + grp * 16384);
  const f16_t* Bs = (const f16_t*)(lds + grp * 16384 + 8192);
  char* ldsA = lds + grp * 16384 + (wl << 10);
  char* ldsB = lds + grp * 16384 + 8192 + (wl << 10);
  const int kb = grp * khalf;
  const f16_t* Ap0 = A + (size_t)(m0 + srow) * K + kb + scol;
  const f16_t* Ap1 = A + (size_t)(m0 + 64 + srow) * K + kb + scol;
  const f16_t* Bp0 = B + (size_t)(n0 + srow) * K + kb + scol;
  const f16_t* Bp1 = B + (size_t)(n0 + 64 + srow) * K + kb + scol;
  for (int k0 = 0; k0 < khalf; k0 += 32) {
    gload16(Ap0 + k0, ldsA);
    gload16(Ap1 + k0, ldsA + 4096);
    gload16(Bp0 + k0, ldsB);
    gload16(Bp1 + k0, ldsB + 4096);
    __syncthreads();
    half8 af[4], bfr[4];
#pragma unroll
    for (int i = 0; i < 4; ++i)
      af[i] = *(const half8*)(As + ((wm + i * 16 + fm) << 5) + fks);
#pragma unroll
    for (int j = 0; j < 4; ++j)
      bfr[j] = *(const half8*)(Bs + ((wn + j * 16 + fm) << 5) + fks);
#pragma unroll
    for (int i = 0; i < 4; ++i)
#pragma unroll
      for (int j = 0; j < 4; ++j)
        acc[i][j] = __builtin_amdgcn_mfma_f32_16x16x32_f16(af[i], bfr[j], acc[i][j], 0, 0, 0);
    __syncthreads();
  }
  // Reduce grp1 partials into grp0. Two rounds of 2 quads (2 x 16 KB in LDS).
  float* red = (float*)lds;
#pragma unroll
  for (int round = 0; round < 2; ++round) {
    const int q0 = round << 1;
    if (grp == 1 && (wl == q0 || wl == q0 + 1)) {
      float* dst = red + (wl - q0) * 4096;
#pragma unroll
      for (int i = 0; i < 4; ++i)
#pragma unroll
        for (int j = 0; j < 4; ++j)
          *(f32x4*)(dst + (((i << 2) + j) << 8) + (lane << 2)) = acc[i][j];
    }
    __syncthreads();
    if (grp == 0 && (wl == q0 || wl == q0 + 1)) {
      const float* src = red + (wl - q0) * 4096;
#pragma unroll
      for (int i = 0; i < 4; ++i)
#pragma unroll
        for (int j = 0; j < 4; ++j) {
          const f32x4 p = *(const f32x4*)(src + (((i << 2) + j) << 8) + (lane << 2));
          acc[i][j] += p;
        }
    }
    __syncthreads();
  }
}

// C/D layout (verified m89): col = lane&15, row = (lane>>4)*4 + reg
#define EPI_PREAMBLE                                            \
  const int lane = threadIdx.x & 63;                            \
  const int wl_e = (threadIdx.x >> 6) & 3;                      \
  const int mb = m0 + ((wl_e & 1) << 6) + ((lane >> 4) << 2);   \
  const int nb = n0 + ((wl_e >> 1) << 6) + (lane & 15);

#define ZERO_ACC                                                \
  f32x4 acc[4][4];                                              \
  _Pragma("unroll")                                             \
  for (int i = 0; i < 4; ++i)                                   \
    _Pragma("unroll")                                           \
    for (int j = 0; j < 4; ++j) acc[i][j] = (f32x4){0.f, 0.f, 0.f, 0.f};

// Merged Q/K/V projection (natural mapping; R3 XCD remap reverted).
// z=0 -> Q, z=1 -> K (row-major f16), z=2 -> V^T via LDS transpose epilogue.
__global__ __launch_bounds__(512, 4)
void k_proj(const f16_t* __restrict__ X,
            const f16_t* __restrict__ Wq, const f16_t* __restrict__ Wk,
            const f16_t* __restrict__ Wv,
            f16_t* __restrict__ Qo, f16_t* __restrict__ Ko,
            u16* __restrict__ Vt) {
  __shared__ char lds[32768];
  ZERO_ACC
  const int z = blockIdx.z;
  const f16_t* W = (z == 0) ? Wq : (z == 1) ? Wk : Wv;
  const int m0 = blockIdx.y << 7, n0 = blockIdx.x << 7;
  gemm_tile_sk2(X, W, C_DIM, C_DIM, m0, n0, lds, acc);
  if (z < 2) {
    if (threadIdx.x < 256) {                 // grp0 holds the sums
      EPI_PREAMBLE
      f16_t* Cb = z ? Ko : Qo;
#pragma unroll
      for (int i = 0; i < 4; ++i)
#pragma unroll
        for (int j = 0; j < 4; ++j) {
          const size_t base = (size_t)(mb + i * 16) * H_DIM + (nb + j * 16);
#pragma unroll
          for (int r = 0; r < 4; ++r)
            Cb[base + (size_t)r * H_DIM] = (f16_t)acc[i][j][r];
        }
    }
  } else {
    // V^T epilogue: stage [h 64][t 128] (stride 136 f16) in LDS, 2 chunks,
    // then 16B-coalesced stores along t (kills the 4x write amplification).
    const int lane2 = threadIdx.x & 63;
    const int wlv = (threadIdx.x >> 6) & 3;
    const int grp = threadIdx.x >> 8;
    const int quad = lane2 >> 4, fmv = lane2 & 15;
    const int wmv = (wlv & 1) << 6;
    const int bb = m0 >> 11;                 // batch
    const int t0v = m0 & (T_SEQ - 1);
    f16_t* Lt = (f16_t*)lds;
#pragma unroll
    for (int c = 0; c < 2; ++c) {
      __syncthreads();
      if (grp == 0 && ((wlv >> 1) == c)) {   // the 2 grp0 waves with wn == c*64
#pragma unroll
        for (int j = 0; j < 4; ++j) {
          const int h_c = (j << 4) + fmv;    // 0..63 within chunk
#pragma unroll
          for (int i = 0; i < 4; ++i) {
            const int t_l = wmv + (i << 4) + (quad << 2);
            f16_t* dst = Lt + h_c * 136 + t_l;
            dst[0] = (f16_t)acc[i][j][0];
            dst[1] = (f16_t)acc[i][j][1];
            dst[2] = (f16_t)acc[i][j][2];
            dst[3] = (f16_t)acc[i][j][3];
          }
        }
      }
      __syncthreads();
#pragma unroll
      for (int p = 0; p < 2; ++p) {
        const int idx = (p << 9) + threadIdx.x;   // 0..1023
        const int h_l = idx >> 4;                 // 0..63
        const int ch = (idx & 15) << 3;           // 0..120
        const half8 v = *(const half8*)(Lt + h_l * 136 + ch);
        *(half8*)((f16_t*)Vt + ((size_t)(bb * H_DIM + n0 + (c << 6) + h_l)) * T_SEQ
                  + t0v + ch) = v;
      }
    }
  }
}

// scores: lower-triangle tiles only, 8-wave split-K. S stored f16 (scaled).
__global__ __launch_bounds__(512, 4)
void k_scores(const f16_t* __restrict__ Q, const f16_t* __restrict__ Kc,
              f16_t* __restrict__ S) {
  __shared__ char lds[32768];
  ZERO_ACC
  const int p = blockIdx.x;                // 0..135 lower-triangle tile id
  int i = (int)((sqrtf(8.f * p + 1.f) - 1.f) * 0.5f);
  while ((i + 1) * (i + 2) / 2 <= p) ++i;
  while (i * (i + 1) / 2 > p) --i;
  const int j = p - i * (i + 1) / 2;
  const int b = blockIdx.y;
  const int m0 = i << 7, n0 = j << 7;
  const f16_t* Aq = Q + (size_t)b * T_SEQ * H_DIM;
  const f16_t* Bk = Kc + (size_t)b * T_SEQ * H_DIM;
  f16_t* Sb = S + (size_t)b * T_SEQ * T_SEQ;
  gemm_tile_sk2(Aq, Bk, H_DIM, H_DIM, m0, n0, lds, acc);
  if (threadIdx.x >> 8) return;            // grp1 has no sums
  EPI_PREAMBLE
  const float scale = 0.022097086912079608f;  // 2048^-0.5
#pragma unroll
  for (int i2 = 0; i2 < 4; ++i2)
#pragma unroll
    for (int j2 = 0; j2 < 4; ++j2) {
      const size_t base = (size_t)(mb + i2 * 16) * T_SEQ + (nb + j2 * 16);
#pragma unroll
      for (int r = 0; r < 4; ++r)
        Sb[base + (size_t)r * T_SEQ] = (f16_t)(acc[i2][j2][r] * scale);
    }
}

// causal softmax row-wise: S f16 -> P f16 (zeros above diagonal)
__global__ __launch_bounds__(256)
void k_softmax(const f16_t* __restrict__ S, f16_t* __restrict__ P) {
  const int row = blockIdx.x;              // b*T + t
  const int t = row & (T_SEQ - 1);
  const int n = t + 1;
  const int tid = threadIdx.x;
  const f16_t* s = S + (size_t)row * T_SEQ;
  f16_t* p = P + (size_t)row * T_SEQ;
  __shared__ float buf[T_SEQ];
  __shared__ float red[8];
  float lmax = -3.0e38f;
  for (int c = tid; c < n; c += 256) lmax = fmaxf(lmax, (float)s[c]);
#pragma unroll
  for (int off = 32; off > 0; off >>= 1) lmax = fmaxf(lmax, __shfl_xor(lmax, off, 64));
  if ((tid & 63) == 0) red[tid >> 6] = lmax;
  __syncthreads();
  const float m = fmaxf(fmaxf(red[0], red[1]), fmaxf(red[2], red[3]));
  float lsum = 0.f;
  for (int c = tid; c < n; c += 256) {
    float e = __expf((float)s[c] - m);
    buf[c] = e;
    lsum += e;
  }
#pragma unroll
  for (int off = 32; off > 0; off >>= 1) lsum += __shfl_xor(lsum, off, 64);
  if ((tid & 63) == 0) red[4 + (tid >> 6)] = lsum;
  __syncthreads();
  const float inv = 1.0f / (red[4] + red[5] + red[6] + red[7]);
  for (int c = tid; c < T_SEQ; c += 256)
    p[c] = (c < n) ? (f16_t)(buf[c] * inv) : (f16_t)0.f;
}

// PV with diagonal pairing: block (n, q, b) computes m-tiles 15-q and q
// (uniform 17 tile-units of K per block; grid = 512 = one balanced round).
__global__ __launch_bounds__(512, 4)
void k_pv(const f16_t* __restrict__ P, const f16_t* __restrict__ Vt,
          float* __restrict__ Out) {
  __shared__ char lds[32768];
  const int b = blockIdx.z;
  const int n0 = blockIdx.x << 7;
  const f16_t* Ap = P + (size_t)b * T_SEQ * T_SEQ;
  const f16_t* Bv = Vt + (size_t)b * H_DIM * T_SEQ;
  float* Ob = Out + (size_t)b * T_SEQ * H_DIM;
#pragma unroll
  for (int u = 0; u < 2; ++u) {
    const int mi = u ? blockIdx.y : (15 - blockIdx.y);   // big K first
    const int m0 = mi << 7;
    ZERO_ACC
    gemm_tile_sk2(Ap, Bv, T_SEQ, m0 + 128, m0, n0, lds, acc);
    if (!(threadIdx.x >> 8)) {
      EPI_PREAMBLE
#pragma unroll
      for (int i = 0; i < 4; ++i)
#pragma unroll
        for (int j = 0; j < 4; ++j) {
          const size_t base = (size_t)(mb + i * 16) * H_DIM + (nb + j * 16);
#pragma unroll
          for (int r = 0; r < 4; ++r)
            Ob[base + (size_t)r * H_DIM] = acc[i][j][r];
        }
    }
  }
}

// one fused f32 -> f16 conversion pass over x, Wk, Wq, Wv
#define XN4 ((B_SZ * T_SEQ * C_DIM) / 4)   // 2097152
#define WN4 ((H_DIM * C_DIM) / 4)          // 524288
__global__ __launch_bounds__(256)
void k_cvt_all(const float4* __restrict__ x,  const float4* __restrict__ wk,
               const float4* __restrict__ wq, const float4* __restrict__ wv,
               ushort4* __restrict__ xb, ushort4* __restrict__ wkb,
               ushort4* __restrict__ wqb, ushort4* __restrict__ wvb) {
  int idx = blockIdx.x * 256 + threadIdx.x;
  const float4* src; ushort4* dst;
  if (idx < XN4)                { src = x;  dst = xb; }
  else if (idx < XN4 + WN4)     { src = wk; dst = wkb; idx -= XN4; }
  else if (idx < XN4 + 2 * WN4) { src = wq; dst = wqb; idx -= XN4 + WN4; }
  else                          { src = wv; dst = wvb; idx -= XN4 + 2 * WN4; }
  const float4 v = src[idx];
  ushort4 o;
  o.x = __builtin_bit_cast(u16, (f16_t)v.x);
  o.y = __builtin_bit_cast(u16, (f16_t)v.y);
  o.z = __builtin_bit_cast(u16, (f16_t)v.z);
  o.w = __builtin_bit_cast(u16, (f16_t)v.w);
  dst[idx] = o;
}

extern "C" void kernel_launch(void* const* d_in, const int* in_sizes, int n_in,
                              void* d_out, int out_size, void* d_ws, size_t ws_size,
                              hipStream_t stream) {
  (void)in_sizes; (void)n_in; (void)out_size; (void)ws_size;
  const float* x  = (const float*)d_in[0];
  const float* Wk = (const float*)d_in[1];
  const float* Wq = (const float*)d_in[2];
  const float* Wv = (const float*)d_in[3];
  float* out = (float*)d_out;
  char* ws = (char*)d_ws;
  // workspace (192 MB):
  //  [0,32M) q f16   [32M,64M) k f16   [64M,96M) Vt f16 [B,H,T]
  //  [96M,128M) S f16 [B,T,T]          [160M,192M) P f16
  //  cvt temps (dead before S written): xb@96M, wk@128M, wq@132M, wv@136M
  f16_t* qb  = (f16_t*)(ws);
  f16_t* kb  = (f16_t*)(ws + (32ull << 20));
  f16_t* vt  = (f16_t*)(ws + (64ull << 20));
  f16_t* S   = (f16_t*)(ws + (96ull << 20));
  f16_t* P   = (f16_t*)(ws + (160ull << 20));
  f16_t* xb  = (f16_t*)(ws + (96ull << 20));
  f16_t* wkb = (f16_t*)(ws + (128ull << 20));
  f16_t* wqb = (f16_t*)(ws + (132ull << 20));
  f16_t* wvb = (f16_t*)(ws + (136ull << 20));

  k_cvt_all<<<(XN4 + 3 * WN4) / 256, 256, 0, stream>>>(
      (const float4*)x, (const float4*)Wk, (const float4*)Wq, (const float4*)Wv,
      (ushort4*)xb, (ushort4*)wkb, (ushort4*)wqb, (ushort4*)wvb);

  dim3 gp(H_DIM / 128, (B_SZ * T_SEQ) / 128, 3);       // 16 x 64 x 3, natural
  k_proj<<<gp, 512, 0, stream>>>(xb, wqb, wkb, wvb, qb, kb, (u16*)vt);

  dim3 gs(136, B_SZ);                                   // lower-triangle tiles
  k_scores<<<gs, 512, 0, stream>>>(qb, kb, S);
  k_softmax<<<B_SZ * T_SEQ, 256, 0, stream>>>(S, P);
  dim3 gv(T_SEQ / 128, 8, B_SZ);                        // paired m-tiles
  k_pv<<<gv, 512, 0, stream>>>(P, vt, out);
}

// Round 5
// 408.698 us; speedup vs baseline: 1.0228x; 1.0066x over previous
//
#include <hip/hip_runtime.h>
#include <math.h>

typedef _Float16 f16_t;
typedef _Float16 half8 __attribute__((ext_vector_type(8)));
typedef float f32x4 __attribute__((ext_vector_type(4)));
typedef float f32x16 __attribute__((ext_vector_type(16)));
typedef unsigned short u16;

#define T_SEQ 2048
#define H_DIM 2048
#define C_DIM 1024
#define B_SZ  4

// async global->LDS, 16B per lane. LDS dest = wave-uniform base + lane*16.
__device__ __forceinline__ void gload16(const void* g, void* l) {
  typedef const __attribute__((address_space(1))) unsigned int* gp_t;
  typedef __attribute__((address_space(3))) unsigned int* lp_t;
  __builtin_amdgcn_global_load_lds((gp_t)(unsigned long long)g,
                                   (lp_t)(unsigned int)(unsigned long long)l,
                                   16, 0, 0);
}

// LDS swizzle (R3: verified conflicts -> 0): LDS[row][c] holds global chunk
// c ^ ((row>>1)&3); fetch side permutes, ds_read de-swizzles.

// ---- 4-wave 32x32-MFMA core (256 thr): 128x128 tile, BK=64 (2 sub-bufs,
// ---- one barrier pair per 64-K). LDS = 32 KB: A[2][128][32], B[2][128][32].
__device__ __forceinline__ void gemm_tile32(const f16_t* __restrict__ A,
                                            const f16_t* __restrict__ B,
                                            int K, int k_end, int m0, int n0,
                                            char* lds, f32x16 acc[2][2]) {
  const int tid  = threadIdx.x;
  const int wave = tid >> 6;
  const int lane = tid & 63;
  const int wm = (wave & 1) << 6;
  const int wn = (wave >> 1) << 6;
  const int srow = tid >> 2;
  const int scol = ((tid & 3) ^ ((tid >> 3) & 3)) << 3;  // swizzled fetch chunk
  const int fm = lane & 31;              // row within a 32-block
  const int kg = lane >> 5;              // k-group 0,1 (k = kg*8 + j)
  char* ldsA = lds + (wave << 10);       // wave-uniform staging base (sub-buf 0)
  char* ldsB = lds + 16384 + (wave << 10);
  const f16_t* Ap0 = A + (size_t)(m0 + srow) * K + scol;
  const f16_t* Ap1 = A + (size_t)(m0 + 64 + srow) * K + scol;
  const f16_t* Bp0 = B + (size_t)(n0 + srow) * K + scol;
  const f16_t* Bp1 = B + (size_t)(n0 + 64 + srow) * K + scol;
  for (int k0 = 0; k0 < k_end; k0 += 64) {
    gload16(Ap0 + k0, ldsA);
    gload16(Ap1 + k0, ldsA + 4096);
    gload16(Ap0 + k0 + 32, ldsA + 8192);
    gload16(Ap1 + k0 + 32, ldsA + 8192 + 4096);
    gload16(Bp0 + k0, ldsB);
    gload16(Bp1 + k0, ldsB + 4096);
    gload16(Bp0 + k0 + 32, ldsB + 8192);
    gload16(Bp1 + k0 + 32, ldsB + 8192 + 4096);
    __syncthreads();
#pragma unroll
    for (int s = 0; s < 4; ++s) {        // 4 k-steps of 16
      const int hb = (s >> 1) << 13;     // sub-buffer byte offset
      const int ks = s & 1;              // 16-k step within sub-buffer
      half8 af[2], bf2[2];
#pragma unroll
      for (int mi = 0; mi < 2; ++mi) {
        const int row = wm + mi * 32 + fm;
        const int ch = ((ks << 1) + kg) ^ ((row >> 1) & 3);
        af[mi] = *(const half8*)(lds + hb + (row << 6) + (ch << 4));
      }
#pragma unroll
      for (int nj = 0; nj < 2; ++nj) {
        const int row = wn + nj * 32 + fm;
        const int ch = ((ks << 1) + kg) ^ ((row >> 1) & 3);
        bf2[nj] = *(const half8*)(lds + 16384 + hb + (row << 6) + (ch << 4));
      }
#pragma unroll
      for (int mi = 0; mi < 2; ++mi)
#pragma unroll
        for (int nj = 0; nj < 2; ++nj)
          acc[mi][nj] = __builtin_amdgcn_mfma_f32_32x32x16_f16(af[mi], bf2[nj], acc[mi][nj], 0, 0, 0);
    }
    __syncthreads();
  }
}

// ------- 8-wave split-K core (512 thr): two groups halve K, LDS-reduce ------
// (16x16x32 MFMA; used by scores/pv where K is long. Unchanged from R4.)
__device__ __forceinline__ void gemm_tile_sk2(const f16_t* __restrict__ A,
                                              const f16_t* __restrict__ B,
                                              int K, int k_end, int m0, int n0,
                                              char* lds, f32x4 acc[4][4]) {
  const int tid  = threadIdx.x;            // 0..511
  const int grp  = tid >> 8;               // 0,1  (waves 0-3 / 4-7)
  const int ltid = tid & 255;
  const int wl   = ltid >> 6;              // local wave 0..3
  const int lane = tid & 63;
  const int wm = (wl & 1) << 6;
  const int wn = (wl >> 1) << 6;
  const int srow = ltid >> 2;
  const int scol = ((ltid & 3) ^ ((ltid >> 3) & 3)) << 3;   // swizzled fetch chunk
  const int fm = lane & 15;
  const int fks = (((lane >> 4) ^ ((lane >> 1) & 3)) << 3); // swizzled read offset
  const int khalf = k_end >> 1;            // multiple of 32
  const f16_t* As = (const f16_t*)(lds + grp * 16384);
  const f16_t* Bs = (const f16_t*)(lds + grp * 16384 + 8192);
  char* ldsA = lds + grp * 16384 + (wl << 10);
  char* ldsB = lds + grp * 16384 + 8192 + (wl << 10);
  const int kb = grp * khalf;
  const f16_t* Ap0 = A + (size_t)(m0 + srow) * K + kb + scol;
  const f16_t* Ap1 = A + (size_t)(m0 + 64 + srow) * K + kb + scol;
  const f16_t* Bp0 = B + (size_t)(n0 + srow) * K + kb + scol;
  const f16_t* Bp1 = B + (size_t)(n0 + 64 + srow) * K + kb + scol;
  for (int k0 = 0; k0 < khalf; k0 += 32) {
    gload16(Ap0 + k0, ldsA);
    gload16(Ap1 + k0, ldsA + 4096);
    gload16(Bp0 + k0, ldsB);
    gload16(Bp1 + k0, ldsB + 4096);
    __syncthreads();
    half8 af[4], bfr[4];
#pragma unroll
    for (int i = 0; i < 4; ++i)
      af[i] = *(const half8*)(As + ((wm + i * 16 + fm) << 5) + fks);
#pragma unroll
    for (int j = 0; j < 4; ++j)
      bfr[j] = *(const half8*)(Bs + ((wn + j * 16 + fm) << 5) + fks);
#pragma unroll
    for (int i = 0; i < 4; ++i)
#pragma unroll
      for (int j = 0; j < 4; ++j)
        acc[i][j] = __builtin_amdgcn_mfma_f32_16x16x32_f16(af[i], bfr[j], acc[i][j], 0, 0, 0);
    __syncthreads();
  }
  // Reduce grp1 partials into grp0. Two rounds of 2 quads (2 x 16 KB in LDS).
  float* red = (float*)lds;
#pragma unroll
  for (int round = 0; round < 2; ++round) {
    const int q0 = round << 1;
    if (grp == 1 && (wl == q0 || wl == q0 + 1)) {
      float* dst = red + (wl - q0) * 4096;
#pragma unroll
      for (int i = 0; i < 4; ++i)
#pragma unroll
        for (int j = 0; j < 4; ++j)
          *(f32x4*)(dst + (((i << 2) + j) << 8) + (lane << 2)) = acc[i][j];
    }
    __syncthreads();
    if (grp == 0 && (wl == q0 || wl == q0 + 1)) {
      const float* src = red + (wl - q0) * 4096;
#pragma unroll
      for (int i = 0; i < 4; ++i)
#pragma unroll
        for (int j = 0; j < 4; ++j) {
          const f32x4 p = *(const f32x4*)(src + (((i << 2) + j) << 8) + (lane << 2));
          acc[i][j] += p;
        }
    }
    __syncthreads();
  }
}

// C/D layout 16x16 (verified m89): col = lane&15, row = (lane>>4)*4 + reg
#define EPI_PREAMBLE                                            \
  const int lane = threadIdx.x & 63;                            \
  const int wl_e = (threadIdx.x >> 6) & 3;                      \
  const int mb = m0 + ((wl_e & 1) << 6) + ((lane >> 4) << 2);   \
  const int nb = n0 + ((wl_e >> 1) << 6) + (lane & 15);

#define ZERO_ACC                                                \
  f32x4 acc[4][4];                                              \
  _Pragma("unroll")                                             \
  for (int i = 0; i < 4; ++i)                                   \
    _Pragma("unroll")                                           \
    for (int j = 0; j < 4; ++j) acc[i][j] = (f32x4){0.f, 0.f, 0.f, 0.f};

// Merged Q/K/V projection: 4-wave 32x32 core, BK=64. Direct stores
// (R4 measured: scattered Vt ushort4 stores are line-combined in L2; ideal WRITE).
// C/D layout 32x32 (verified m74/m101): col=lane&31, row=(reg&3)+8*(reg>>2)+4*(lane>>5)
__global__ __launch_bounds__(256, 2)
void k_proj(const f16_t* __restrict__ X,
            const f16_t* __restrict__ Wq, const f16_t* __restrict__ Wk,
            const f16_t* __restrict__ Wv,
            f16_t* __restrict__ Qo, f16_t* __restrict__ Ko,
            u16* __restrict__ Vt) {
  __shared__ char lds[32768];
  f32x16 acc[2][2];
#pragma unroll
  for (int i = 0; i < 2; ++i)
#pragma unroll
    for (int j = 0; j < 2; ++j)
#pragma unroll
      for (int r = 0; r < 16; ++r) acc[i][j][r] = 0.f;
  const int z = blockIdx.z;
  const f16_t* W = (z == 0) ? Wq : (z == 1) ? Wk : Wv;
  const int m0 = blockIdx.y << 7, n0 = blockIdx.x << 7;
  gemm_tile32(X, W, C_DIM, C_DIM, m0, n0, lds, acc);
  const int lane = threadIdx.x & 63;
  const int wave = threadIdx.x >> 6;
  const int rb = m0 + ((wave & 1) << 6) + ((lane >> 5) << 2);  // +i*32+(r&3)+8*(r>>2)
  const int cb = n0 + ((wave >> 1) << 6) + (lane & 31);        // +j*32
  if (z < 2) {
    f16_t* Cb = z ? Ko : Qo;
#pragma unroll
    for (int i = 0; i < 2; ++i)
#pragma unroll
      for (int j = 0; j < 2; ++j) {
        const int col = cb + j * 32;
#pragma unroll
        for (int r = 0; r < 16; ++r) {
          const int row = rb + i * 32 + (r & 3) + ((r >> 2) << 3);
          Cb[(size_t)row * H_DIM + col] = (f16_t)acc[i][j][r];
        }
      }
  } else {
#pragma unroll
    for (int i = 0; i < 2; ++i)
#pragma unroll
      for (int q = 0; q < 4; ++q) {
        const int gm = rb + i * 32 + (q << 3);   // b*T + t (4 consecutive t)
        const int b = gm >> 11;
        const int t = gm & (T_SEQ - 1);
#pragma unroll
        for (int j = 0; j < 2; ++j) {
          const int h = cb + j * 32;
          ushort4 pk;
          pk.x = __builtin_bit_cast(u16, (f16_t)acc[i][j][4 * q + 0]);
          pk.y = __builtin_bit_cast(u16, (f16_t)acc[i][j][4 * q + 1]);
          pk.z = __builtin_bit_cast(u16, (f16_t)acc[i][j][4 * q + 2]);
          pk.w = __builtin_bit_cast(u16, (f16_t)acc[i][j][4 * q + 3]);
          *(ushort4*)(Vt + ((size_t)(b * H_DIM + h) * T_SEQ + t)) = pk;
        }
      }
  }
}

// scores: lower-triangle tiles only, 8-wave split-K. S stored f16 (scaled).
__global__ __launch_bounds__(512, 4)
void k_scores(const f16_t* __restrict__ Q, const f16_t* __restrict__ Kc,
              f16_t* __restrict__ S) {
  __shared__ char lds[32768];
  ZERO_ACC
  const int p = blockIdx.x;                // 0..135 lower-triangle tile id
  int i = (int)((sqrtf(8.f * p + 1.f) - 1.f) * 0.5f);
  while ((i + 1) * (i + 2) / 2 <= p) ++i;
  while (i * (i + 1) / 2 > p) --i;
  const int j = p - i * (i + 1) / 2;
  const int b = blockIdx.y;
  const int m0 = i << 7, n0 = j << 7;
  const f16_t* Aq = Q + (size_t)b * T_SEQ * H_DIM;
  const f16_t* Bk = Kc + (size_t)b * T_SEQ * H_DIM;
  f16_t* Sb = S + (size_t)b * T_SEQ * T_SEQ;
  gemm_tile_sk2(Aq, Bk, H_DIM, H_DIM, m0, n0, lds, acc);
  if (threadIdx.x >> 8) return;            // grp1 has no sums
  EPI_PREAMBLE
  const float scale = 0.022097086912079608f;  // 2048^-0.5
#pragma unroll
  for (int i2 = 0; i2 < 4; ++i2)
#pragma unroll
    for (int j2 = 0; j2 < 4; ++j2) {
      const size_t base = (size_t)(mb + i2 * 16) * T_SEQ + (nb + j2 * 16);
#pragma unroll
      for (int r = 0; r < 4; ++r)
        Sb[base + (size_t)r * T_SEQ] = (f16_t)(acc[i2][j2][r] * scale);
    }
}

// causal softmax row-wise: S f16 -> P f16 (zeros above diagonal)
__global__ __launch_bounds__(256)
void k_softmax(const f16_t* __restrict__ S, f16_t* __restrict__ P) {
  const int row = blockIdx.x;              // b*T + t
  const int t = row & (T_SEQ - 1);
  const int n = t + 1;
  const int tid = threadIdx.x;
  const f16_t* s = S + (size_t)row * T_SEQ;
  f16_t* p = P + (size_t)row * T_SEQ;
  __shared__ float buf[T_SEQ];
  __shared__ float red[8];
  float lmax = -3.0e38f;
  for (int c = tid; c < n; c += 256) lmax = fmaxf(lmax, (float)s[c]);
#pragma unroll
  for (int off = 32; off > 0; off >>= 1) lmax = fmaxf(lmax, __shfl_xor(lmax, off, 64));
  if ((tid & 63) == 0) red[tid >> 6] = lmax;
  __syncthreads();
  const float m = fmaxf(fmaxf(red[0], red[1]), fmaxf(red[2], red[3]));
  float lsum = 0.f;
  for (int c = tid; c < n; c += 256) {
    float e = __expf((float)s[c] - m);
    buf[c] = e;
    lsum += e;
  }
#pragma unroll
  for (int off = 32; off > 0; off >>= 1) lsum += __shfl_xor(lsum, off, 64);
  if ((tid & 63) == 0) red[4 + (tid >> 6)] = lsum;
  __syncthreads();
  const float inv = 1.0f / (red[4] + red[5] + red[6] + red[7]);
  for (int c = tid; c < T_SEQ; c += 256)
    p[c] = (c < n) ? (f16_t)(buf[c] * inv) : (f16_t)0.f;
}

// PV with diagonal pairing: block (n, q, b) computes m-tiles 15-q and q
// (uniform 17 tile-units of K per block; grid = 512 = one balanced round).
__global__ __launch_bounds__(512, 4)
void k_pv(const f16_t* __restrict__ P, const f16_t* __restrict__ Vt,
          float* __restrict__ Out) {
  __shared__ char lds[32768];
  const int b = blockIdx.z;
  const int n0 = blockIdx.x << 7;
  const f16_t* Ap = P + (size_t)b * T_SEQ * T_SEQ;
  const f16_t* Bv = Vt + (size_t)b * H_DIM * T_SEQ;
  float* Ob = Out + (size_t)b * T_SEQ * H_DIM;
#pragma unroll
  for (int u = 0; u < 2; ++u) {
    const int mi = u ? blockIdx.y : (15 - blockIdx.y);   // big K first
    const int m0 = mi << 7;
    ZERO_ACC
    gemm_tile_sk2(Ap, Bv, T_SEQ, m0 + 128, m0, n0, lds, acc);
    if (!(threadIdx.x >> 8)) {
      EPI_PREAMBLE
#pragma unroll
      for (int i = 0; i < 4; ++i)
#pragma unroll
        for (int j = 0; j < 4; ++j) {
          const size_t base = (size_t)(mb + i * 16) * H_DIM + (nb + j * 16);
#pragma unroll
          for (int r = 0; r < 4; ++r)
            Ob[base + (size_t)r * H_DIM] = acc[i][j][r];
        }
    }
  }
}

// one fused f32 -> f16 conversion pass over x, Wk, Wq, Wv
#define XN4 ((B_SZ * T_SEQ * C_DIM) / 4)   // 2097152
#define WN4 ((H_DIM * C_DIM) / 4)          // 524288
__global__ __launch_bounds__(256)
void k_cvt_all(const float4* __restrict__ x,  const float4* __restrict__ wk,
               const float4* __restrict__ wq, const float4* __restrict__ wv,
               ushort4* __restrict__ xb, ushort4* __restrict__ wkb,
               ushort4* __restrict__ wqb, ushort4* __restrict__ wvb) {
  int idx = blockIdx.x * 256 + threadIdx.x;
  const float4* src; ushort4* dst;
  if (idx < XN4)                { src = x;  dst = xb; }
  else if (idx < XN4 + WN4)     { src = wk; dst = wkb; idx -= XN4; }
  else if (idx < XN4 + 2 * WN4) { src = wq; dst = wqb; idx -= XN4 + WN4; }
  else                          { src = wv; dst = wvb; idx -= XN4 + 2 * WN4; }
  const float4 v = src[idx];
  ushort4 o;
  o.x = __builtin_bit_cast(u16, (f16_t)v.x);
  o.y = __builtin_bit_cast(u16, (f16_t)v.y);
  o.z = __builtin_bit_cast(u16, (f16_t)v.z);
  o.w = __builtin_bit_cast(u16, (f16_t)v.w);
  dst[idx] = o;
}

extern "C" void kernel_launch(void* const* d_in, const int* in_sizes, int n_in,
                              void* d_out, int out_size, void* d_ws, size_t ws_size,
                              hipStream_t stream) {
  (void)in_sizes; (void)n_in; (void)out_size; (void)ws_size;
  const float* x  = (const float*)d_in[0];
  const float* Wk = (const float*)d_in[1];
  const float* Wq = (const float*)d_in[2];
  const float* Wv = (const float*)d_in[3];
  float* out = (float*)d_out;
  char* ws = (char*)d_ws;
  // workspace (192 MB):
  //  [0,32M) q f16   [32M,64M) k f16   [64M,96M) Vt f16 [B,H,T]
  //  [96M,128M) S f16 [B,T,T]          [160M,192M) P f16
  //  cvt temps (dead before S written): xb@96M, wk@128M, wq@132M, wv@136M
  f16_t* qb  = (f16_t*)(ws);
  f16_t* kb  = (f16_t*)(ws + (32ull << 20));
  f16_t* vt  = (f16_t*)(ws + (64ull << 20));
  f16_t* S   = (f16_t*)(ws + (96ull << 20));
  f16_t* P   = (f16_t*)(ws + (160ull << 20));
  f16_t* xb  = (f16_t*)(ws + (96ull << 20));
  f16_t* wkb = (f16_t*)(ws + (128ull << 20));
  f16_t* wqb = (f16_t*)(ws + (132ull << 20));
  f16_t* wvb = (f16_t*)(ws + (136ull << 20));

  k_cvt_all<<<(XN4 + 3 * WN4) / 256, 256, 0, stream>>>(
      (const float4*)x, (const float4*)Wk, (const float4*)Wq, (const float4*)Wv,
      (ushort4*)xb, (ushort4*)wkb, (ushort4*)wqb, (ushort4*)wvb);

  dim3 gp(H_DIM / 128, (B_SZ * T_SEQ) / 128, 3);       // 16 x 64 x 3, natural
  k_proj<<<gp, 256, 0, stream>>>(xb, wqb, wkb, wvb, qb, kb, (u16*)vt);

  dim3 gs(136, B_SZ);                                   // lower-triangle tiles
  k_scores<<<gs, 512, 0, stream>>>(qb, kb, S);
  k_softmax<<<B_SZ * T_SEQ, 256, 0, stream>>>(S, P);
  dim3 gv(T_SEQ / 128, 8, B_SZ);                        // paired m-tiles
  k_pv<<<gv, 512, 0, stream>>>(P, vt, out);
}

// Round 6
// 383.729 us; speedup vs baseline: 1.0894x; 1.0651x over previous
//
#include <hip/hip_runtime.h>
#include <math.h>

typedef _Float16 f16_t;
typedef _Float16 half8 __attribute__((ext_vector_type(8)));
typedef float f32x4 __attribute__((ext_vector_type(4)));
typedef unsigned short u16;

#define T_SEQ 2048
#define H_DIM 2048
#define C_DIM 1024
#define B_SZ  4

// async global->LDS, 16B per lane. LDS dest = wave-uniform base + lane*16.
__device__ __forceinline__ void gload16(const void* g, void* l) {
  typedef const __attribute__((address_space(1))) unsigned int* gp_t;
  typedef __attribute__((address_space(3))) unsigned int* lp_t;
  __builtin_amdgcn_global_load_lds((gp_t)(unsigned long long)g,
                                   (lp_t)(unsigned int)(unsigned long long)l,
                                   16, 0, 0);
}

// LDS swizzle (R3: measured 0 conflicts with the 16x16 read pattern):
// phys[row][c] holds global chunk c ^ ((row>>1)&3); fetch permutes, read
// de-swizzles via fks. R5's 32x32 pattern measured 4 cyc/ds_read conflicts
// -> reverted to this pattern.

// -- 4-wave 16x16 core, BK=64 (2 sub-buffers, ONE barrier pair per 64-K) --
// LDS = 32 KB: A[2][128][32] f16 @0, B[2][128][32] f16 @16384.
__device__ __forceinline__ void gemm_tile64(const f16_t* __restrict__ A,
                                            const f16_t* __restrict__ B,
                                            int K, int k_end, int m0, int n0,
                                            char* lds, f32x4 acc[4][4]) {
  const int tid  = threadIdx.x;
  const int wave = tid >> 6;
  const int lane = tid & 63;
  const int wm = (wave & 1) << 6;
  const int wn = (wave >> 1) << 6;
  const int srow = tid >> 2;
  const int scol = ((tid & 3) ^ ((tid >> 3) & 3)) << 3;     // swizzled fetch chunk
  const int fm = lane & 15;
  const int fks = (((lane >> 4) ^ ((lane >> 1) & 3)) << 3); // swizzled read offset
  const f16_t* As = (const f16_t*)lds;
  const f16_t* Bs = (const f16_t*)(lds + 16384);
  char* ldsA = lds + (wave << 10);
  char* ldsB = lds + 16384 + (wave << 10);
  const f16_t* Ap0 = A + (size_t)(m0 + srow) * K + scol;
  const f16_t* Ap1 = A + (size_t)(m0 + 64 + srow) * K + scol;
  const f16_t* Bp0 = B + (size_t)(n0 + srow) * K + scol;
  const f16_t* Bp1 = B + (size_t)(n0 + 64 + srow) * K + scol;
  for (int k0 = 0; k0 < k_end; k0 += 64) {
    gload16(Ap0 + k0, ldsA);
    gload16(Ap1 + k0, ldsA + 4096);
    gload16(Ap0 + k0 + 32, ldsA + 8192);
    gload16(Ap1 + k0 + 32, ldsA + 12288);
    gload16(Bp0 + k0, ldsB);
    gload16(Bp1 + k0, ldsB + 4096);
    gload16(Bp0 + k0 + 32, ldsB + 8192);
    gload16(Bp1 + k0 + 32, ldsB + 12288);
    __syncthreads();
#pragma unroll
    for (int s = 0; s < 2; ++s) {
      const f16_t* As_s = As + (s << 12);
      const f16_t* Bs_s = Bs + (s << 12);
      half8 af[4], bfr[4];
#pragma unroll
      for (int i = 0; i < 4; ++i)
        af[i] = *(const half8*)(As_s + ((wm + i * 16 + fm) << 5) + fks);
#pragma unroll
      for (int j = 0; j < 4; ++j)
        bfr[j] = *(const half8*)(Bs_s + ((wn + j * 16 + fm) << 5) + fks);
#pragma unroll
      for (int i = 0; i < 4; ++i)
#pragma unroll
        for (int j = 0; j < 4; ++j)
          acc[i][j] = __builtin_amdgcn_mfma_f32_16x16x32_f16(af[i], bfr[j], acc[i][j], 0, 0, 0);
    }
    __syncthreads();
  }
}

// ------- 8-wave split-K core (512 thr): two groups halve K, LDS-reduce ------
__device__ __forceinline__ void gemm_tile_sk2(const f16_t* __restrict__ A,
                                              const f16_t* __restrict__ B,
                                              int K, int k_end, int m0, int n0,
                                              char* lds, f32x4 acc[4][4]) {
  const int tid  = threadIdx.x;            // 0..511
  const int grp  = tid >> 8;               // 0,1  (waves 0-3 / 4-7)
  const int ltid = tid & 255;
  const int wl   = ltid >> 6;              // local wave 0..3
  const int lane = tid & 63;
  const int wm = (wl & 1) << 6;
  const int wn = (wl >> 1) << 6;
  const int srow = ltid >> 2;
  const int scol = ((ltid & 3) ^ ((ltid >> 3) & 3)) << 3;   // swizzled fetch chunk
  const int fm = lane & 15;
  const int fks = (((lane >> 4) ^ ((lane >> 1) & 3)) << 3); // swizzled read offset
  const int khalf = k_end >> 1;            // multiple of 32
  const f16_t* As = (const f16_t*)(lds + grp * 16384);
  const f16_t* Bs = (const f16_t*)(lds + grp * 16384 + 8192);
  char* ldsA = lds + grp * 16384 + (wl << 10);
  char* ldsB = lds + grp * 16384 + 8192 + (wl << 10);
  const int kb = grp * khalf;
  const f16_t* Ap0 = A + (size_t)(m0 + srow) * K + kb + scol;
  const f16_t* Ap1 = A + (size_t)(m0 + 64 + srow) * K + kb + scol;
  const f16_t* Bp0 = B + (size_t)(n0 + srow) * K + kb + scol;
  const f16_t* Bp1 = B + (size_t)(n0 + 64 + srow) * K + kb + scol;
  for (int k0 = 0; k0 < khalf; k0 += 32) {
    gload16(Ap0 + k0, ldsA);
    gload16(Ap1 + k0, ldsA + 4096);
    gload16(Bp0 + k0, ldsB);
    gload16(Bp1 + k0, ldsB + 4096);
    __syncthreads();
    half8 af[4], bfr[4];
#pragma unroll
    for (int i = 0; i < 4; ++i)
      af[i] = *(const half8*)(As + ((wm + i * 16 + fm) << 5) + fks);
#pragma unroll
    for (int j = 0; j < 4; ++j)
      bfr[j] = *(const half8*)(Bs + ((wn + j * 16 + fm) << 5) + fks);
#pragma unroll
    for (int i = 0; i < 4; ++i)
#pragma unroll
      for (int j = 0; j < 4; ++j)
        acc[i][j] = __builtin_amdgcn_mfma_f32_16x16x32_f16(af[i], bfr[j], acc[i][j], 0, 0, 0);
    __syncthreads();
  }
  // Reduce grp1 partials into grp0. Two rounds of 2 quads (2 x 16 KB in LDS).
  float* red = (float*)lds;
#pragma unroll
  for (int round = 0; round < 2; ++round) {
    const int q0 = round << 1;
    if (grp == 1 && (wl == q0 || wl == q0 + 1)) {
      float* dst = red + (wl - q0) * 4096;
#pragma unroll
      for (int i = 0; i < 4; ++i)
#pragma unroll
        for (int j = 0; j < 4; ++j)
          *(f32x4*)(dst + (((i << 2) + j) << 8) + (lane << 2)) = acc[i][j];
    }
    __syncthreads();
    if (grp == 0 && (wl == q0 || wl == q0 + 1)) {
      const float* src = red + (wl - q0) * 4096;
#pragma unroll
      for (int i = 0; i < 4; ++i)
#pragma unroll
        for (int j = 0; j < 4; ++j) {
          const f32x4 p = *(const f32x4*)(src + (((i << 2) + j) << 8) + (lane << 2));
          acc[i][j] += p;
        }
    }
    __syncthreads();
  }
}

// C/D layout 16x16 (verified m89): col = lane&15, row = (lane>>4)*4 + reg
#define EPI_PREAMBLE                                            \
  const int lane = threadIdx.x & 63;                            \
  const int wl_e = (threadIdx.x >> 6) & 3;                      \
  const int mb = m0 + ((wl_e & 1) << 6) + ((lane >> 4) << 2);   \
  const int nb = n0 + ((wl_e >> 1) << 6) + (lane & 15);

#define ZERO_ACC                                                \
  f32x4 acc[4][4];                                              \
  _Pragma("unroll")                                             \
  for (int i = 0; i < 4; ++i)                                   \
    _Pragma("unroll")                                           \
    for (int j = 0; j < 4; ++j) acc[i][j] = (f32x4){0.f, 0.f, 0.f, 0.f};

// Merged Q/K/V projection: 4-wave 16x16 core, BK=64, natural block mapping.
__global__ __launch_bounds__(256, 2)
void k_proj(const f16_t* __restrict__ X,
            const f16_t* __restrict__ Wq, const f16_t* __restrict__ Wk,
            const f16_t* __restrict__ Wv,
            f16_t* __restrict__ Qo, f16_t* __restrict__ Ko,
            u16* __restrict__ Vt) {
  __shared__ char lds[32768];
  ZERO_ACC
  const int z = blockIdx.z;
  const f16_t* W = (z == 0) ? Wq : (z == 1) ? Wk : Wv;
  const int m0 = blockIdx.y << 7, n0 = blockIdx.x << 7;
  gemm_tile64(X, W, C_DIM, C_DIM, m0, n0, lds, acc);
  EPI_PREAMBLE
  if (z < 2) {
    f16_t* Cb = z ? Ko : Qo;
#pragma unroll
    for (int i = 0; i < 4; ++i)
#pragma unroll
      for (int j = 0; j < 4; ++j) {
        const size_t base = (size_t)(mb + i * 16) * H_DIM + (nb + j * 16);
#pragma unroll
        for (int r = 0; r < 4; ++r)
          Cb[base + (size_t)r * H_DIM] = (f16_t)acc[i][j][r];
      }
  } else {
    // Vt stores: R4 measured scattered ushort4 stores are line-combined (ideal WRITE)
#pragma unroll
    for (int i = 0; i < 4; ++i) {
      const int gm = mb + i * 16;          // b*T + t
      const int b = gm >> 11;
      const int t = gm & (T_SEQ - 1);
#pragma unroll
      for (int j = 0; j < 4; ++j) {
        const int h = nb + j * 16;
        ushort4 pk;
        pk.x = __builtin_bit_cast(u16, (f16_t)acc[i][j][0]);
        pk.y = __builtin_bit_cast(u16, (f16_t)acc[i][j][1]);
        pk.z = __builtin_bit_cast(u16, (f16_t)acc[i][j][2]);
        pk.w = __builtin_bit_cast(u16, (f16_t)acc[i][j][3]);
        *(ushort4*)(Vt + ((size_t)(b * H_DIM + h) * T_SEQ + t)) = pk;
      }
    }
  }
}

// scores: lower-triangle tiles only, 8-wave split-K. S stored f16 (scaled).
__global__ __launch_bounds__(512, 4)
void k_scores(const f16_t* __restrict__ Q, const f16_t* __restrict__ Kc,
              f16_t* __restrict__ S) {
  __shared__ char lds[32768];
  ZERO_ACC
  const int p = blockIdx.x;                // 0..135 lower-triangle tile id
  int i = (int)((sqrtf(8.f * p + 1.f) - 1.f) * 0.5f);
  while ((i + 1) * (i + 2) / 2 <= p) ++i;
  while (i * (i + 1) / 2 > p) --i;
  const int j = p - i * (i + 1) / 2;
  const int b = blockIdx.y;
  const int m0 = i << 7, n0 = j << 7;
  const f16_t* Aq = Q + (size_t)b * T_SEQ * H_DIM;
  const f16_t* Bk = Kc + (size_t)b * T_SEQ * H_DIM;
  f16_t* Sb = S + (size_t)b * T_SEQ * T_SEQ;
  gemm_tile_sk2(Aq, Bk, H_DIM, H_DIM, m0, n0, lds, acc);
  if (threadIdx.x >> 8) return;            // grp1 has no sums
  EPI_PREAMBLE
  const float scale = 0.022097086912079608f;  // 2048^-0.5
#pragma unroll
  for (int i2 = 0; i2 < 4; ++i2)
#pragma unroll
    for (int j2 = 0; j2 < 4; ++j2) {
      const size_t base = (size_t)(mb + i2 * 16) * T_SEQ + (nb + j2 * 16);
#pragma unroll
      for (int r = 0; r < 4; ++r)
        Sb[base + (size_t)r * T_SEQ] = (f16_t)(acc[i2][j2][r] * scale);
    }
}

// causal softmax: one row/block, one half8/thread, exp kept in registers.
// Writes zeros only up to n128 = ceil(n/128)*128 — exactly the region PV reads.
__global__ __launch_bounds__(256)
void k_softmax(const f16_t* __restrict__ S, f16_t* __restrict__ P) {
  const int row = blockIdx.x;              // b*T + t
  const int t = row & (T_SEQ - 1);
  const int n = t + 1;
  const int n128 = (n + 127) & ~127;
  const int tid = threadIdx.x;
  const int c0 = tid << 3;
  const f16_t* s = S + (size_t)row * T_SEQ;
  f16_t* p = P + (size_t)row * T_SEQ;
  __shared__ float red[8];
  half8 v;
  float lmax = -3.0e38f;
  if (c0 < n) {
    v = *(const half8*)(s + c0);
#pragma unroll
    for (int r = 0; r < 8; ++r)
      if (c0 + r < n) lmax = fmaxf(lmax, (float)v[r]);
  }
#pragma unroll
  for (int off = 32; off > 0; off >>= 1) lmax = fmaxf(lmax, __shfl_xor(lmax, off, 64));
  if ((tid & 63) == 0) red[tid >> 6] = lmax;
  __syncthreads();
  const float m = fmaxf(fmaxf(red[0], red[1]), fmaxf(red[2], red[3]));
  float e[8];
  float lsum = 0.f;
  if (c0 < n) {
#pragma unroll
    for (int r = 0; r < 8; ++r) {
      e[r] = (c0 + r < n) ? __expf((float)v[r] - m) : 0.f;
      lsum += e[r];
    }
  }
#pragma unroll
  for (int off = 32; off > 0; off >>= 1) lsum += __shfl_xor(lsum, off, 64);
  if ((tid & 63) == 0) red[4 + (tid >> 6)] = lsum;
  __syncthreads();
  const float inv = 1.0f / (red[4] + red[5] + red[6] + red[7]);
  if (c0 < n128) {
    half8 o;
#pragma unroll
    for (int r = 0; r < 8; ++r)
      o[r] = (c0 + r < n) ? (f16_t)(e[r] * inv) : (f16_t)0.f;
    *(half8*)(p + c0) = o;
  }
}

// PV with diagonal pairing: block (n, q, b) computes m-tiles 15-q and q
// (uniform 17 tile-units of K per block; grid = 512 = one balanced round).
__global__ __launch_bounds__(512, 4)
void k_pv(const f16_t* __restrict__ P, const f16_t* __restrict__ Vt,
          float* __restrict__ Out) {
  __shared__ char lds[32768];
  const int b = blockIdx.z;
  const int n0 = blockIdx.x << 7;
  const f16_t* Ap = P + (size_t)b * T_SEQ * T_SEQ;
  const f16_t* Bv = Vt + (size_t)b * H_DIM * T_SEQ;
  float* Ob = Out + (size_t)b * T_SEQ * H_DIM;
#pragma unroll
  for (int u = 0; u < 2; ++u) {
    const int mi = u ? blockIdx.y : (15 - blockIdx.y);   // big K first
    const int m0 = mi << 7;
    ZERO_ACC
    gemm_tile_sk2(Ap, Bv, T_SEQ, m0 + 128, m0, n0, lds, acc);
    if (!(threadIdx.x >> 8)) {
      EPI_PREAMBLE
#pragma unroll
      for (int i = 0; i < 4; ++i)
#pragma unroll
        for (int j = 0; j < 4; ++j) {
          const size_t base = (size_t)(mb + i * 16) * H_DIM + (nb + j * 16);
#pragma unroll
          for (int r = 0; r < 4; ++r)
            Ob[base + (size_t)r * H_DIM] = acc[i][j][r];
        }
    }
  }
}

// one fused f32 -> f16 conversion pass over x, Wk, Wq, Wv
#define XN4 ((B_SZ * T_SEQ * C_DIM) / 4)   // 2097152
#define WN4 ((H_DIM * C_DIM) / 4)          // 524288
__global__ __launch_bounds__(256)
void k_cvt_all(const float4* __restrict__ x,  const float4* __restrict__ wk,
               const float4* __restrict__ wq, const float4* __restrict__ wv,
               ushort4* __restrict__ xb, ushort4* __restrict__ wkb,
               ushort4* __restrict__ wqb, ushort4* __restrict__ wvb) {
  int idx = blockIdx.x * 256 + threadIdx.x;
  const float4* src; ushort4* dst;
  if (idx < XN4)                { src = x;  dst = xb; }
  else if (idx < XN4 + WN4)     { src = wk; dst = wkb; idx -= XN4; }
  else if (idx < XN4 + 2 * WN4) { src = wq; dst = wqb; idx -= XN4 + WN4; }
  else                          { src = wv; dst = wvb; idx -= XN4 + 2 * WN4; }
  const float4 v = src[idx];
  ushort4 o;
  o.x = __builtin_bit_cast(u16, (f16_t)v.x);
  o.y = __builtin_bit_cast(u16, (f16_t)v.y);
  o.z = __builtin_bit_cast(u16, (f16_t)v.z);
  o.w = __builtin_bit_cast(u16, (f16_t)v.w);
  dst[idx] = o;
}

extern "C" void kernel_launch(void* const* d_in, const int* in_sizes, int n_in,
                              void* d_out, int out_size, void* d_ws, size_t ws_size,
                              hipStream_t stream) {
  (void)in_sizes; (void)n_in; (void)out_size; (void)ws_size;
  const float* x  = (const float*)d_in[0];
  const float* Wk = (const float*)d_in[1];
  const float* Wq = (const float*)d_in[2];
  const float* Wv = (const float*)d_in[3];
  float* out = (float*)d_out;
  char* ws = (char*)d_ws;
  // workspace (192 MB):
  //  [0,32M) q f16   [32M,64M) k f16   [64M,96M) Vt f16 [B,H,T]
  //  [96M,128M) S f16 [B,T,T]          [160M,192M) P f16
  //  cvt temps (dead before S written): xb@96M, wk@128M, wq@132M, wv@136M
  f16_t* qb  = (f16_t*)(ws);
  f16_t* kb  = (f16_t*)(ws + (32ull << 20));
  f16_t* vt  = (f16_t*)(ws + (64ull << 20));
  f16_t* S   = (f16_t*)(ws + (96ull << 20));
  f16_t* P   = (f16_t*)(ws + (160ull << 20));
  f16_t* xb  = (f16_t*)(ws + (96ull << 20));
  f16_t* wkb = (f16_t*)(ws + (128ull << 20));
  f16_t* wqb = (f16_t*)(ws + (132ull << 20));
  f16_t* wvb = (f16_t*)(ws + (136ull << 20));

  k_cvt_all<<<(XN4 + 3 * WN4) / 256, 256, 0, stream>>>(
      (const float4*)x, (const float4*)Wk, (const float4*)Wq, (const float4*)Wv,
      (ushort4*)xb, (ushort4*)wkb, (ushort4*)wqb, (ushort4*)wvb);

  dim3 gp(H_DIM / 128, (B_SZ * T_SEQ) / 128, 3);       // 16 x 64 x 3, natural
  k_proj<<<gp, 256, 0, stream>>>(xb, wqb, wkb, wvb, qb, kb, (u16*)vt);

  dim3 gs(136, B_SZ);                                   // lower-triangle tiles
  k_scores<<<gs, 512, 0, stream>>>(qb, kb, S);
  k_softmax<<<B_SZ * T_SEQ, 256, 0, stream>>>(S, P);
  dim3 gv(T_SEQ / 128, 8, B_SZ);                        // paired m-tiles
  k_pv<<<gv, 512, 0, stream>>>(P, vt, out);
}